// Round 3
// 441.951 us; speedup vs baseline: 1.3301x; 1.3301x over previous
//
#include <hip/hip_runtime.h>
#include <stdint.h>

#define N 8192
#define G 7
#define T 512
#define NW 8          // waves per block
typedef unsigned long long u64;
typedef uint32_t u32;

// Map float bits -> uint32 such that ascending uint order == DESCENDING float
// order, XLA total-order semantics. Stable LSD radix handles index tie-break.
__device__ __forceinline__ u32 enc_desc(float x) {
    u32 u = __float_as_uint(x);
    return (u & 0x80000000u) ? u : (~u & 0x7FFFFFFFu);
}
__device__ __forceinline__ float dec_desc(u32 k) {
    u32 u = (k & 0x80000000u) ? k : (~k & 0x7FFFFFFFu);
    return __uint_as_float(u);
}

__global__ __launch_bounds__(T) void portfolio_radix_kernel(
    const float* __restrict__ x,
    float* __restrict__ bc,        // [B, N] float32
    float* __restrict__ idx_out)   // [B, N] indices as float32
{
    __shared__ u64 data[N];          // 64 KiB
    __shared__ u32 wcnt[NW * 256];   // 8 KiB  per-wave digit counters / bases
    __shared__ u32 dsum[256];        // 1 KiB  global digit exclusive bases
    __shared__ u32 wsum[4];          // chunk sums for 256-wide scan

    const int t    = threadIdx.x;
    const int w    = t >> 6;         // wave 0..7
    const int lane = t & 63;
    const int row  = blockIdx.x;
    const float* xr = x + (size_t)row * N;

    // Element ownership: e = 1024*w + 64*j + lane  (order = (w, j, lane), which
    // matches the rank composition: wave-base + earlier-element atomic order)
    u64 key[16];
#pragma unroll
    for (int j = 0; j < 16; ++j) {
        int e = (w << 10) | (j << 6) | lane;
        key[j] = ((u64)enc_desc(xr[e]) << 32) | (u32)e;
    }

    u32 rank[16];

    for (int p = 0; p < 4; ++p) {
        const int shift = 8 * p;     // applied to hi word of key

        // ---- zero per-wave counters ----
#pragma unroll
        for (int i = 0; i < 4; ++i) wcnt[t + T * i] = 0;
        __syncthreads();

        // ---- phase A: stable in-wave rank via LDS atomic (ds_add_rtn_u32) ----
        // Per-wave private counters: no cross-wave races. Ordering across the
        // 16 j-iterations is program order (same-wave DS ops are ordered).
        // Ordering across lanes within one instruction relies on the LDS
        // arbiter serializing same-address atomics in ascending lane order
        // (consistent with the "highest lane wins" same-address write rule).
        // NOTE: even if that order assumption is wrong, rank[] is still a
        // permutation of [0,N) (unique consecutive atomic returns + exact
        // partition by digit bases) -> scatter stays in-bounds; failure mode
        // is a loud verification miss, never a fault.
#pragma unroll
        for (int j = 0; j < 16; ++j) {
            u32 hi = (u32)(key[j] >> 32);
            u32 d  = (hi >> shift) & 255u;
            rank[j] = atomicAdd(&wcnt[(w << 8) | d], 1u);
        }
        __syncthreads();

        // ---- phase B: scan. threads 0..255 own one digit each ----
        if (t < 256) {
            u32 run = 0;
#pragma unroll
            for (int ww = 0; ww < NW; ++ww) {    // serial over waves: exclusive
                u32 c = wcnt[(ww << 8) | t];     // per-wave count for this digit
                wcnt[(ww << 8) | t] = run;
                run += c;
            }
            // run = total count of digit t; shuffle inclusive scan over 64 digits
            u32 v = run;
#pragma unroll
            for (int off = 1; off < 64; off <<= 1) {
                u32 u = __shfl_up(v, off, 64);
                if (lane >= off) v += u;
            }
            if (lane == 63) wsum[w] = v;         // chunk total (w = 0..3 here)
            dsum[t] = v - run;                   // exclusive within chunk
        }
        __syncthreads();
        if (t < 256) {
            u32 add = 0;
            if (w > 0) add += wsum[0];
            if (w > 1) add += wsum[1];
            if (w > 2) add += wsum[2];
            dsum[t] += add;                      // global exclusive digit base
        }
        __syncthreads();
        // fold digit base into per-wave bases: wcnt[w][d] += dsum[d]
#pragma unroll
        for (int i = 0; i < 4; ++i) {
            int id = t + T * i;
            wcnt[id] += dsum[id & 255];
        }
        __syncthreads();

        // ---- scatter ----
#pragma unroll
        for (int j = 0; j < 16; ++j) {
            u32 hi = (u32)(key[j] >> 32);
            u32 d  = (hi >> shift) & 255u;
            rank[j] += wcnt[(w << 8) | d];       // final position
        }
#pragma unroll
        for (int j = 0; j < 16; ++j) data[rank[j]] = key[j];
        __syncthreads();

        if (p < 3) {
#pragma unroll
            for (int j = 0; j < 16; ++j) {
                int e = (w << 10) | (j << 6) | lane;
                key[j] = data[e];
            }
        }
    }

    // ---- outputs: data[] sorted ascending in enc == descending in x ----
    float* bcr = bc + (size_t)row * N;
    float* ixr = idx_out + (size_t)row * N;
#pragma unroll
    for (int j = 0; j < 16; ++j) {
        int e = (w << 10) | (j << 6) | lane;     // per-slot coalesced stores
        u64 kk = data[e];
        ixr[e] = (float)(u32)(kk & 0xFFFFFFFFu);
        bcr[e] = 0.0f;
    }
    // winner: threads 0..6 each redundantly compute softmax(top-7), write own slot.
    // Overwrites this thread's own j=0 zero-write (same thread, program order: safe).
    if (t < G) {
        float s[G], ex[G], sum = 0.f;
#pragma unroll
        for (int g = 0; g < G; ++g) s[g] = dec_desc((u32)(data[g] >> 32));
        float m0 = s[0];                          // max (descending values)
#pragma unroll
        for (int g = 0; g < G; ++g) { ex[g] = expf(s[g] - m0); sum += ex[g]; }
        bcr[t] = ex[t] / sum;
    }
    // loser: threads 505..511 (w=7, j=15 slots) -> positions N-G..N-1.
    // -softmax(1 - bottom) == -softmax(-bottom) (shift invariance)
    if (t >= T - G) {
        float s[G], ex[G], sum = 0.f;
#pragma unroll
        for (int g = 0; g < G; ++g) s[g] = dec_desc((u32)(data[N - G + g] >> 32));
        float m0 = -s[G - 1];                     // max of -s (s descending)
#pragma unroll
        for (int g = 0; g < G; ++g) { ex[g] = expf(-s[g] - m0); sum += ex[g]; }
        bcr[(N - T) + t] = -ex[t - (T - G)] / sum;
    }
}

extern "C" void kernel_launch(void* const* d_in, const int* in_sizes, int n_in,
                              void* d_out, int out_size, void* d_ws, size_t ws_size,
                              hipStream_t stream) {
    const float* x = (const float*)d_in[0];
    float* out = (float*)d_out;
    const int B = in_sizes[0] / N;               // 4096
    float* bc  = out;                             // output 0: [B, N]
    float* idx = out + (size_t)B * N;             // output 1: [B, N] (as float32)
    portfolio_radix_kernel<<<B, T, 0, stream>>>(x, bc, idx);
}